// Round 1
// baseline (520.383 us; speedup 1.0000x reference)
//
#include <hip/hip_runtime.h>
#include <math.h>

#define MAXN 0.996f          /* (1 - 4e-3) / sqrt(c) */
#define MINN 1e-15f
#define ATEPS (1.0f - 1e-7f)

typedef __attribute__((address_space(3))) void lds_t;
typedef const __attribute__((address_space(1))) void gbl_t;

__device__ __forceinline__ void glds16(const float* g, float* l) {
  __builtin_amdgcn_global_load_lds((gbl_t*)g, (lds_t*)l, 16, 0, 0);
}

__device__ __forceinline__ float dot4(float4 a, float4 b) {
  return a.x*b.x + a.y*b.y + a.z*b.z + a.w*b.w;
}

__device__ __forceinline__ float red32(float v) {
  v += __shfl_xor(v, 1);
  v += __shfl_xor(v, 2);
  v += __shfl_xor(v, 4);
  v += __shfl_xor(v, 8);
  v += __shfl_xor(v, 16);
  return v;
}

#define FMA4(A, S, B4) do { \
  (A).x = fmaf((S), (B4).x, (A).x); \
  (A).y = fmaf((S), (B4).y, (A).y); \
  (A).z = fmaf((S), (B4).z, (A).z); \
  (A).w = fmaf((S), (B4).w, (A).w); } while (0)

#define SCL4(A, S) do { (A).x *= (S); (A).y *= (S); (A).z *= (S); (A).w *= (S); } while (0)

// out[C][R] = in[R][C]  (R, C multiples of 32)
__global__ void tkern(const float* __restrict__ in, float* __restrict__ out, int R, int C) {
  __shared__ float tl[32][33];
  int bx = blockIdx.x * 32, by = blockIdx.y * 32;
  int x = threadIdx.x, y = threadIdx.y;
#pragma unroll
  for (int m = 0; m < 4; m++) tl[y + 8*m][x] = in[(size_t)(by + y + 8*m) * C + bx + x];
  __syncthreads();
#pragma unroll
  for (int m = 0; m < 4; m++) out[(size_t)(bx + y + 8*m) * R + by + x] = tl[x][y + 8*m];
}

__global__ __launch_bounds__(256, 2) void hyper(
    const float* __restrict__ X,    // [B,256]
    const float* __restrict__ b1,   // [512]
    const float* __restrict__ b2,   // [128]
    const float* __restrict__ W1T,  // [256,512]
    const float* __restrict__ W2T,  // [512,128]
    float* __restrict__ out)        // [B,128]
{
  __shared__ float xs[32 * 256];   // X tile, reused as h-tile halves for layer 2
  __shared__ float wt[64 * 128];   // W tile (k-major)
  __shared__ float xnl[32];

  const int t  = threadIdx.x;
  const int w  = t >> 6;           // wave 0..3
  const int ln = t & 63;           // lane
  const int tr = t >> 5;           // row group 0..7  (rows 4*tr..4*tr+3)
  const int tc = t & 31;           // col group 0..31 (cols 4*tc..4*tc+3 per 128-chunk)
  const size_t rowBase = (size_t)blockIdx.x * 32;

  // ---------------- stage X tile (contiguous 32KB) ----------------
  {
    const float* xg = X + rowBase * 256;
#pragma unroll
    for (int m = 0; m < 8; m++) {
      int q = w * 8 + m;
      glds16(xg + q * 256 + 4 * ln, xs + q * 256);
    }
  }
  __syncthreads();

  // ---------------- per-row ||x|| ----------------
  {
    int r = t >> 3, s = t & 7;
    float ss = 0.f;
#pragma unroll
    for (int m = 0; m < 8; m++) {
      float4 v = *(const float4*)&xs[r * 256 + 4 * (s + 8 * m)];
      ss += dot4(v, v);
    }
    ss += __shfl_xor(ss, 1); ss += __shfl_xor(ss, 2); ss += __shfl_xor(ss, 4);
    if (s == 0) xnl[r] = sqrtf(ss);
  }

  // ---------------- GEMM1: mx = x @ W1^T   (32 x 512) ----------------
  float4 acc[4][4];  // [nn-chunk][row i], cols 4*tc..4*tc+3
#pragma unroll
  for (int nn = 0; nn < 4; nn++)
#pragma unroll
    for (int i = 0; i < 4; i++) acc[nn][i] = make_float4(0.f, 0.f, 0.f, 0.f);

#pragma unroll
  for (int nn = 0; nn < 4; nn++) {
    for (int kt = 0; kt < 4; kt++) {
      __syncthreads();  // previous wt reads done
#pragma unroll
      for (int m = 0; m < 8; m++) {
        int q = w * 8 + m;
        glds16(W1T + (size_t)(kt * 64 + 2 * q + (ln >> 5)) * 512 + nn * 128 + 4 * (ln & 31),
               wt + q * 256);
      }
      __syncthreads();
#pragma unroll 4
      for (int k0 = 0; k0 < 64; k0 += 4) {
        float4 xr[4], wr[4];
#pragma unroll
        for (int i = 0; i < 4; i++) xr[i] = *(const float4*)&xs[(4 * tr + i) * 256 + kt * 64 + k0];
#pragma unroll
        for (int u = 0; u < 4; u++) wr[u] = *(const float4*)&wt[(k0 + u) * 128 + 4 * tc];
#pragma unroll
        for (int i = 0; i < 4; i++) {
          FMA4(acc[nn][i], xr[i].x, wr[0]);
          FMA4(acc[nn][i], xr[i].y, wr[1]);
          FMA4(acc[nn][i], xr[i].z, wr[2]);
          FMA4(acc[nn][i], xr[i].w, wr[3]);
        }
      }
    }
  }

  // ---------------- layer-1 epilogue ----------------
  // mobius_matvec scale + project
  float hn[4];
  {
    float s2[4];
#pragma unroll
    for (int i = 0; i < 4; i++) {
      float ss = 0.f;
#pragma unroll
      for (int nn = 0; nn < 4; nn++) ss += dot4(acc[nn][i], acc[nn][i]);
      s2[i] = red32(ss);
    }
#pragma unroll
    for (int i = 0; i < 4; i++) {
      float xnv = fmaxf(xnl[4 * tr + i], MINN);
      float mxn = fmaxf(sqrtf(s2[i]), MINN);
      float tv  = tanhf(mxn / xnv * atanhf(fminf(xnv, ATEPS)));
      float sc  = tv / mxn;
      float h   = fmaxf(tv, MINN);
      if (h > MAXN) { sc *= MAXN / h; h = MAXN; }
      hn[i] = h;
#pragma unroll
      for (int nn = 0; nn < 4; nn++) SCL4(acc[nn][i], sc);
    }
  }

  // mobius_add(h, b1) + project
  float gn[4];
  {
    float4 b1v[4];
#pragma unroll
    for (int nn = 0; nn < 4; nn++) b1v[nn] = *(const float4*)&b1[nn * 128 + 4 * tc];
    float y2p = 0.f;
#pragma unroll
    for (int nn = 0; nn < 4; nn++) y2p += dot4(b1v[nn], b1v[nn]);
    float y2 = red32(y2p);
    float xy[4];
#pragma unroll
    for (int i = 0; i < 4; i++) {
      float p = 0.f;
#pragma unroll
      for (int nn = 0; nn < 4; nn++) p += dot4(acc[nn][i], b1v[nn]);
      xy[i] = red32(p);
    }
#pragma unroll
    for (int i = 0; i < 4; i++) {
      float x2  = hn[i] * hn[i];
      float A   = 1.f + 2.f * xy[i] + y2;
      float Bc  = 1.f - x2;
      float den = fmaxf(1.f + 2.f * xy[i] + x2 * y2, MINN);
      float inv = 1.f / den;
#pragma unroll
      for (int nn = 0; nn < 4; nn++) {
        acc[nn][i].x = (A * acc[nn][i].x + Bc * b1v[nn].x) * inv;
        acc[nn][i].y = (A * acc[nn][i].y + Bc * b1v[nn].y) * inv;
        acc[nn][i].z = (A * acc[nn][i].z + Bc * b1v[nn].z) * inv;
        acc[nn][i].w = (A * acc[nn][i].w + Bc * b1v[nn].w) * inv;
      }
    }
#pragma unroll
    for (int i = 0; i < 4; i++) {
      float ss = 0.f;
#pragma unroll
      for (int nn = 0; nn < 4; nn++) ss += dot4(acc[nn][i], acc[nn][i]);
      float n = fmaxf(sqrtf(red32(ss)), MINN);
      if (n > MAXN) {
        float s = MAXN / n;
#pragma unroll
        for (int nn = 0; nn < 4; nn++) SCL4(acc[nn][i], s);
        n = MAXN;
      }
      gn[i] = n;
    }
  }

  // expmap0(tanh(logmap0(.))) + project  -> h for layer 2 (norm kept in regs)
  float xn2[4];
  {
#pragma unroll
    for (int i = 0; i < 4; i++) {
      float sc3 = atanhf(fminf(gn[i], ATEPS)) / gn[i];
#pragma unroll
      for (int nn = 0; nn < 4; nn++) {
        acc[nn][i].x = tanhf(acc[nn][i].x * sc3);
        acc[nn][i].y = tanhf(acc[nn][i].y * sc3);
        acc[nn][i].z = tanhf(acc[nn][i].z * sc3);
        acc[nn][i].w = tanhf(acc[nn][i].w * sc3);
      }
    }
#pragma unroll
    for (int i = 0; i < 4; i++) {
      float ss = 0.f;
#pragma unroll
      for (int nn = 0; nn < 4; nn++) ss += dot4(acc[nn][i], acc[nn][i]);
      float tn  = fmaxf(sqrtf(red32(ss)), MINN);
      float tv2 = tanhf(tn);
      float sc4 = tv2 / tn;
      float on  = fmaxf(tv2, MINN);
      if (on > MAXN) { sc4 *= MAXN / on; on = MAXN; }
#pragma unroll
      for (int nn = 0; nn < 4; nn++) SCL4(acc[nn][i], sc4);
      xn2[i] = on;
    }
  }

  // ---------------- GEMM2: mx2 = h @ W2^T   (32 x 128), h^T restaged via xs ----------------
  float4 acc2[4];
#pragma unroll
  for (int i = 0; i < 4; i++) acc2[i] = make_float4(0.f, 0.f, 0.f, 0.f);

#pragma unroll
  for (int half = 0; half < 2; half++) {
    __syncthreads();  // previous xs/wt reads done
#pragma unroll
    for (int nn = 0; nn < 2; nn++)
#pragma unroll
      for (int i = 0; i < 4; i++)
        *(float4*)&xs[(4 * tr + i) * 256 + nn * 128 + 4 * tc] = acc[half * 2 + nn][i];
    __syncthreads();
    for (int kt = 0; kt < 4; kt++) {
      if (kt) __syncthreads();
#pragma unroll
      for (int m = 0; m < 8; m++) {
        int q = w * 8 + m;
        glds16(W2T + (size_t)(half * 4 + kt) * 8192 + q * 256 + 4 * ln, wt + q * 256);
      }
      __syncthreads();
#pragma unroll 4
      for (int k0 = 0; k0 < 64; k0 += 4) {
        float4 xr[4], wr[4];
#pragma unroll
        for (int i = 0; i < 4; i++) xr[i] = *(const float4*)&xs[(4 * tr + i) * 256 + kt * 64 + k0];
#pragma unroll
        for (int u = 0; u < 4; u++) wr[u] = *(const float4*)&wt[(k0 + u) * 128 + 4 * tc];
#pragma unroll
        for (int i = 0; i < 4; i++) {
          FMA4(acc2[i], xr[i].x, wr[0]);
          FMA4(acc2[i], xr[i].y, wr[1]);
          FMA4(acc2[i], xr[i].z, wr[2]);
          FMA4(acc2[i], xr[i].w, wr[3]);
        }
      }
    }
  }

  // ---------------- layer-2 epilogue ----------------
  float hn2[4];
#pragma unroll
  for (int i = 0; i < 4; i++) {
    float s2 = red32(dot4(acc2[i], acc2[i]));
    float xnv = xn2[i];
    float mxn = fmaxf(sqrtf(s2), MINN);
    float tv  = tanhf(mxn / xnv * atanhf(fminf(xnv, ATEPS)));
    float sc  = tv / mxn;
    float h   = fmaxf(tv, MINN);
    if (h > MAXN) { sc *= MAXN / h; h = MAXN; }
    hn2[i] = h;
    SCL4(acc2[i], sc);
  }
  {
    float4 b2v = *(const float4*)&b2[4 * tc];
    float y2 = red32(dot4(b2v, b2v));
    float xy[4];
#pragma unroll
    for (int i = 0; i < 4; i++) xy[i] = red32(dot4(acc2[i], b2v));
#pragma unroll
    for (int i = 0; i < 4; i++) {
      float x2  = hn2[i] * hn2[i];
      float A   = 1.f + 2.f * xy[i] + y2;
      float Bc  = 1.f - x2;
      float den = fmaxf(1.f + 2.f * xy[i] + x2 * y2, MINN);
      float inv = 1.f / den;
      acc2[i].x = (A * acc2[i].x + Bc * b2v.x) * inv;
      acc2[i].y = (A * acc2[i].y + Bc * b2v.y) * inv;
      acc2[i].z = (A * acc2[i].z + Bc * b2v.z) * inv;
      acc2[i].w = (A * acc2[i].w + Bc * b2v.w) * inv;
    }
#pragma unroll
    for (int i = 0; i < 4; i++) {
      float n = fmaxf(sqrtf(red32(dot4(acc2[i], acc2[i]))), MINN);
      if (n > MAXN) { float s = MAXN / n; SCL4(acc2[i], s); }
    }
  }
#pragma unroll
  for (int i = 0; i < 4; i++)
    *(float4*)&out[(rowBase + 4 * tr + i) * 128 + 4 * tc] = acc2[i];
}

extern "C" void kernel_launch(void* const* d_in, const int* in_sizes, int n_in,
                              void* d_out, int out_size, void* d_ws, size_t ws_size,
                              hipStream_t stream) {
  const float* x  = (const float*)d_in[0];  // [B,256]
  const float* W1 = (const float*)d_in[1];  // [512,256]
  const float* b1 = (const float*)d_in[2];  // [512]
  const float* W2 = (const float*)d_in[3];  // [128,512]
  const float* b2 = (const float*)d_in[4];  // [128]
  float* o = (float*)d_out;

  const int B = in_sizes[0] / 256;

  float* W1T = (float*)d_ws;          // [256,512]
  float* W2T = W1T + 256 * 512;       // [512,128]

  tkern<<<dim3(256 / 32, 512 / 32), dim3(32, 8), 0, stream>>>(W1, W1T, 512, 256);
  tkern<<<dim3(512 / 32, 128 / 32), dim3(32, 8), 0, stream>>>(W2, W2T, 128, 512);
  hyper<<<B / 32, 256, 0, stream>>>(x, b1, b2, W1T, W2T, o);
}

// Round 2
// 257.438 us; speedup vs baseline: 2.0214x; 2.0214x over previous
//
#include <hip/hip_runtime.h>
#include <hip/hip_bf16.h>
#include <math.h>

#define MAXN 0.996f          /* (1 - 4e-3) / sqrt(c) */
#define MINN 1e-15f
#define ATEPS (1.0f - 1e-7f)

typedef unsigned short u16;
typedef __attribute__((ext_vector_type(8))) short bf16x8;
typedef __attribute__((ext_vector_type(16))) float fx16;
typedef __attribute__((ext_vector_type(4))) float fx4;

typedef __attribute__((address_space(3))) void lds_t;
typedef const __attribute__((address_space(1))) void gbl_t;

__device__ __forceinline__ void glds16(const void* g, void* l) {
  __builtin_amdgcn_global_load_lds((gbl_t*)g, (lds_t*)l, 16, 0, 0);
}

__device__ __forceinline__ u16 f2bf(float v) {
  __hip_bfloat16 h = __float2bfloat16(v);
  union { __hip_bfloat16 b; u16 u; } cv; cv.b = h; return cv.u;
}
__device__ __forceinline__ float bf2f(u16 u) {
  union { u16 u; __hip_bfloat16 b; } cv; cv.u = u; return __bfloat162float(cv.b);
}

__device__ __forceinline__ float dot4(float4 a, float4 b) {
  return a.x*b.x + a.y*b.y + a.z*b.z + a.w*b.w;
}
#define SCL4(A,S) do { (A).x*=(S); (A).y*=(S); (A).z*=(S); (A).w*=(S); } while(0)
#define MADD4(A,Ai,Bi,B) do { \
  (A).x=(Ai)*(A).x+(Bi)*(B).x; (A).y=(Ai)*(A).y+(Bi)*(B).y; \
  (A).z=(Ai)*(A).z+(Bi)*(B).z; (A).w=(Ai)*(A).w+(Bi)*(B).w; } while(0)
#define TANH4(A,S) do { \
  (A).x=tanhf((S)*(A).x); (A).y=tanhf((S)*(A).y); \
  (A).z=tanhf((S)*(A).z); (A).w=tanhf((S)*(A).w); } while(0)

__device__ __forceinline__ float red8f(float v) {   // sum over lanes differing in bits 0..2
  v += __shfl_xor(v, 1); v += __shfl_xor(v, 2); v += __shfl_xor(v, 4);
  return v;
}
__device__ __forceinline__ float red64f(float v) {  // full-wave sum
  v += __shfl_xor(v, 1); v += __shfl_xor(v, 2); v += __shfl_xor(v, 4);
  v += __shfl_xor(v, 8); v += __shfl_xor(v, 16); v += __shfl_xor(v, 32);
  return v;
}

__device__ __forceinline__ fx16 z16() {
  fx16 v;
#pragma unroll
  for (int i = 0; i < 16; i++) v[i] = 0.f;
  return v;
}
__device__ __forceinline__ fx4 z4() {
  fx4 v;
#pragma unroll
  for (int i = 0; i < 4; i++) v[i] = 0.f;
  return v;
}

// ---- split W into hi/lo bf16 planes ----
__global__ void cvtW(const float* __restrict__ W1, const float* __restrict__ W2,
                     u16* __restrict__ w1h, u16* __restrict__ w1l,
                     u16* __restrict__ w2h, u16* __restrict__ w2l) {
  int idx = blockIdx.x * 512 + threadIdx.x;
  if (idx < 512 * 256) {
    float v = W1[idx];
    u16 h = f2bf(v);
    w1h[idx] = h; w1l[idx] = f2bf(v - bf2f(h));
  } else {
    int j = idx - 512 * 256;   // < 128*512
    float v = W2[j];
    u16 h = f2bf(v);
    w2h[j] = h; w2l[j] = f2bf(v - bf2f(h));
  }
}

// W1 slab stage: [512 n][16 k] hi/lo planes, 16KB each; 4 loads per wave
__device__ __forceinline__ void stageW1(char* dst, const u16* __restrict__ w1h,
                                        const u16* __restrict__ w1l, int kt, int w, int l) {
#pragma unroll
  for (int j = 0; j < 4; j++) {
    int idx = w * 4 + j;                               // 0..31
    const u16* src = ((idx & 16) ? w1l : w1h)
                   + ((idx & 15) * 32 + (l >> 1)) * 256 + kt * 16 + (l & 1) * 8;
    glds16(src, dst + (idx >> 4) * 16384 + (idx & 15) * 1024);
  }
}

// W2 slab stage: [128 n][32 k] hi/lo planes, 8KB each; 2 loads per wave
__device__ __forceinline__ void stageW2(char* dst, const u16* __restrict__ w2h,
                                        const u16* __restrict__ w2l, int kt, int w, int l) {
#pragma unroll
  for (int j = 0; j < 2; j++) {
    int idx = w * 2 + j;                               // 0..15
    const u16* src = ((idx & 8) ? w2l : w2h)
                   + ((idx & 7) * 16 + (l >> 2)) * 512 + kt * 32 + (l & 3) * 8;
    glds16(src, dst + (idx >> 3) * 8192 + (idx & 7) * 1024);
  }
}

#define SW(row) (((row) & 7) << 4)

__global__ __launch_bounds__(512, 2) void hyper(
    const float* __restrict__ X,    // [B,256]
    const float* __restrict__ b1,   // [512]
    const float* __restrict__ b2,   // [128]
    const u16* __restrict__ w1h, const u16* __restrict__ w1l,   // [512,256]
    const u16* __restrict__ w2h, const u16* __restrict__ w2l,   // [128,512]
    float* __restrict__ out)        // [B,128]
{
  // LDS map (bytes):
  //  [0,32768)      x hi  [64][256] bf16      -> later: h [64][512] bf16 (0..65536) -> later: mx2 [64][128] f32 (0..32768)
  //  [32768,65536)  x lo
  //  [0,131072)     mx    [64][512] f32 (after GEMM1)
  //  [65536,131072) W1 slabs (2 bufs x 2 planes x 16KB) ; later W2 slabs (2 bufs x 2 planes x 8KB)
  //  [131072,...)   b1s(2KB) b2s(512B) red8(64B) sy(8B)
  __shared__ __align__(16) char smem[131072 + 2688];

  const int t = threadIdx.x;
  const int w = t >> 6;
  const int l = t & 63;
  const int l31 = l & 31, lh = l >> 5, l15 = l & 15, l4 = (l >> 4) & 3;
  const int rr = t >> 3, cc = t & 7;        // row / col-group for phase0 + epilogues
  const long rowBase = (long)blockIdx.x * 64;

  float* red8 = (float*)(smem + 131072 + 2560);
  float* sy   = (float*)(smem + 131072 + 2624);

  // ---------------- prologue: stage W1 slab 0 ----------------
  stageW1(smem + 65536, w1h, w1l, 0, w, l);

  // ---------------- phase 0: x -> LDS (bf16 hi/lo), xn; b1/b2 -> LDS; ||b||^2 ----------------
  float xn;
  {
    const float* xg = X + (rowBase + rr) * 256 + cc * 32;
    float4 v[8];
#pragma unroll
    for (int m = 0; m < 8; m++) v[m] = *(const float4*)(xg + m * 4);
    float ss = 0.f;
#pragma unroll
    for (int m = 0; m < 8; m++) ss += dot4(v[m], v[m]);
    ss = red8f(ss);
    xn = fmaxf(sqrtf(ss), MINN);
#pragma unroll
    for (int m2 = 0; m2 < 4; m2++) {
      union { u16 u[8]; bf16x8 v8; } ph, pl;
      float e0 = v[2*m2].x, e1 = v[2*m2].y, e2 = v[2*m2].z, e3 = v[2*m2].w;
      float e4 = v[2*m2+1].x, e5 = v[2*m2+1].y, e6 = v[2*m2+1].z, e7 = v[2*m2+1].w;
      ph.u[0]=f2bf(e0); pl.u[0]=f2bf(e0-bf2f(ph.u[0]));
      ph.u[1]=f2bf(e1); pl.u[1]=f2bf(e1-bf2f(ph.u[1]));
      ph.u[2]=f2bf(e2); pl.u[2]=f2bf(e2-bf2f(ph.u[2]));
      ph.u[3]=f2bf(e3); pl.u[3]=f2bf(e3-bf2f(ph.u[3]));
      ph.u[4]=f2bf(e4); pl.u[4]=f2bf(e4-bf2f(ph.u[4]));
      ph.u[5]=f2bf(e5); pl.u[5]=f2bf(e5-bf2f(ph.u[5]));
      ph.u[6]=f2bf(e6); pl.u[6]=f2bf(e6-bf2f(ph.u[6]));
      ph.u[7]=f2bf(e7); pl.u[7]=f2bf(e7-bf2f(ph.u[7]));
      int k0 = cc * 32 + m2 * 8;
      int off = ((rr * 256 + k0) * 2) ^ SW(rr);
      *(bf16x8*)(smem + off) = ph.v8;
      *(bf16x8*)(smem + 32768 + off) = pl.v8;
    }
  }
  {
    float bv = b1[t];
    *(float*)(smem + 131072 + ((t * 4) ^ (((t >> 6) & 7) << 4))) = bv;
    float s1 = red64f(bv * bv);
    if (l == 0) red8[w * 2] = s1;
    float bv2 = (t < 128) ? b2[t] : 0.f;
    if (t < 128) *(float*)(smem + 131072 + 2048 + ((t * 4) ^ (((t >> 4) & 7) << 4))) = bv2;
    float s2 = red64f(bv2 * bv2);
    if (l == 0) red8[w * 2 + 1] = s2;
  }
  __syncthreads();
  if (t == 0) {
    float a = 0.f, b = 0.f;
#pragma unroll
    for (int j = 0; j < 8; j++) { a += red8[j * 2]; b += red8[j * 2 + 1]; }
    sy[0] = a; sy[1] = b;
  }

  // ---------------- GEMM1: mx = x @ W1^T  (64 x 512), split-bf16 3-pass ----------------
  fx16 acc[2][2];
#pragma unroll
  for (int a = 0; a < 2; a++)
#pragma unroll
    for (int b = 0; b < 2; b++) acc[a][b] = z16();

  for (int kt = 0; kt < 16; kt++) {
    if (kt < 15) stageW1(smem + 65536 + ((kt + 1) & 1) * 32768, w1h, w1l, kt + 1, w, l);
    const char* buf = smem + 65536 + (kt & 1) * 32768;
    bf16x8 ah[2], al[2], bh[2], bl[2];
#pragma unroll
    for (int mt = 0; mt < 2; mt++) {
      int row = mt * 32 + l31;
      int off = ((row * 256 + kt * 16 + lh * 8) * 2) ^ SW(row);
      ah[mt] = *(const bf16x8*)(smem + off);
      al[mt] = *(const bf16x8*)(smem + 32768 + off);
    }
#pragma unroll
    for (int nt = 0; nt < 2; nt++) {
      int n = w * 64 + nt * 32 + l31;
      int boff = n * 32 + lh * 16;
      bh[nt] = *(const bf16x8*)(buf + boff);
      bl[nt] = *(const bf16x8*)(buf + 16384 + boff);
    }
#pragma unroll
    for (int mt = 0; mt < 2; mt++)
#pragma unroll
      for (int nt = 0; nt < 2; nt++) {
        acc[mt][nt] = __builtin_amdgcn_mfma_f32_32x32x16_bf16(ah[mt], bh[nt], acc[mt][nt], 0, 0, 0);
        acc[mt][nt] = __builtin_amdgcn_mfma_f32_32x32x16_bf16(ah[mt], bl[nt], acc[mt][nt], 0, 0, 0);
        acc[mt][nt] = __builtin_amdgcn_mfma_f32_32x32x16_bf16(al[mt], bh[nt], acc[mt][nt], 0, 0, 0);
      }
    __syncthreads();
  }

  // ---------------- mx -> LDS f32 [64][512], row-swizzled ----------------
#pragma unroll
  for (int mt = 0; mt < 2; mt++)
#pragma unroll
    for (int nt = 0; nt < 2; nt++)
#pragma unroll
      for (int r = 0; r < 16; r++) {
        int row = mt * 32 + (r & 3) + 8 * (r >> 2) + 4 * lh;
        int col = w * 64 + nt * 32 + l31;
        *(float*)(smem + ((row * 2048 + col * 4) ^ SW(row))) = acc[mt][nt][r];
      }
  __syncthreads();

  // ---------------- layer-1 epilogue (row-parallel: 8 threads/row, 64 cols each) ----------------
  float xn2;
  float4 f[16];
  {
    const int c0 = cc * 64;
    float4 bv[16];
#pragma unroll
    for (int ch = 0; ch < 16; ch++)
      f[ch] = *(const float4*)(smem + ((rr * 2048 + (c0 + ch * 4) * 4) ^ SW(rr)));
#pragma unroll
    for (int ch = 0; ch < 16; ch++) {
      int c = c0 + ch * 4;
      bv[ch] = *(const float4*)(smem + 131072 + ((c * 4) ^ (((c >> 6) & 7) << 4)));
    }
    __syncthreads();   // all mx reads done; [0,128K) reusable

    // mobius_matvec scale + project
    float ss = 0.f;
#pragma unroll
    for (int ch = 0; ch < 16; ch++) ss += dot4(f[ch], f[ch]);
    ss = red8f(ss);
    float mxn = fmaxf(sqrtf(ss), MINN);
    float tv = tanhf(mxn / xn * atanhf(fminf(xn, ATEPS)));
    float sc = tv / mxn;
    float hn = tv;
    if (hn > MAXN) { sc *= MAXN / hn; hn = MAXN; }
#pragma unroll
    for (int ch = 0; ch < 16; ch++) SCL4(f[ch], sc);

    // mobius_add(h, b1) + project
    float xyp = 0.f;
#pragma unroll
    for (int ch = 0; ch < 16; ch++) xyp += dot4(f[ch], bv[ch]);
    float xy = red8f(xyp);
    float y2 = sy[0];
    float x2 = hn * hn;
    float A  = 1.f + 2.f * xy + y2;
    float Bc = 1.f - x2;
    float den = fmaxf(1.f + 2.f * xy + x2 * y2, MINN);
    float Ai = A / den, Bi = Bc / den;
#pragma unroll
    for (int ch = 0; ch < 16; ch++) MADD4(f[ch], Ai, Bi, bv[ch]);
    float g2 = 0.f;
#pragma unroll
    for (int ch = 0; ch < 16; ch++) g2 += dot4(f[ch], f[ch]);
    g2 = red8f(g2);
    float gn = fmaxf(sqrtf(g2), MINN);
    float pf  = (gn > MAXN) ? (MAXN / gn) : 1.f;
    float gnp = fminf(gn, MAXN);

    // expmap0(tanh(logmap0(.))) + project
    float csc = pf * atanhf(fminf(gnp, ATEPS)) / gnp;
#pragma unroll
    for (int ch = 0; ch < 16; ch++) TANH4(f[ch], csc);
    float t2 = 0.f;
#pragma unroll
    for (int ch = 0; ch < 16; ch++) t2 += dot4(f[ch], f[ch]);
    t2 = red8f(t2);
    float tn = fmaxf(sqrtf(t2), MINN);
    float tv2 = tanhf(tn);
    float sc4 = tv2 / tn;
    float on = tv2;
    if (on > MAXN) { sc4 *= MAXN / on; on = MAXN; }
    xn2 = fmaxf(on, MINN);
#pragma unroll
    for (int ch = 0; ch < 16; ch++) SCL4(f[ch], sc4);
  }

  // ---------------- h -> LDS bf16 [64][512] + prefetch W2 slab 0 ----------------
  {
    const int c0 = cc * 64;
#pragma unroll
    for (int ch = 0; ch < 8; ch++) {
      union { u16 u[8]; bf16x8 v8; } ph;
      float4 a = f[ch * 2], b = f[ch * 2 + 1];
      ph.u[0]=f2bf(a.x); ph.u[1]=f2bf(a.y); ph.u[2]=f2bf(a.z); ph.u[3]=f2bf(a.w);
      ph.u[4]=f2bf(b.x); ph.u[5]=f2bf(b.y); ph.u[6]=f2bf(b.z); ph.u[7]=f2bf(b.w);
      int off = (rr * 1024 + (c0 + ch * 8) * 2) ^ SW(rr);
      *(bf16x8*)(smem + off) = ph.v8;
    }
    stageW2(smem + 65536, w2h, w2l, 0, w, l);
  }
  __syncthreads();

  // ---------------- GEMM2: mx2 = h @ W2^T  (64 x 128), h bf16, W2 2-pass ----------------
  fx4 acc2[4];
#pragma unroll
  for (int m = 0; m < 4; m++) acc2[m] = z4();

  for (int kt = 0; kt < 16; kt++) {
    if (kt < 15) stageW2(smem + 65536 + ((kt + 1) & 1) * 16384, w2h, w2l, kt + 1, w, l);
    const char* buf = smem + 65536 + (kt & 1) * 16384;
    bf16x8 ah[4], bh, bl;
#pragma unroll
    for (int mt = 0; mt < 4; mt++) {
      int row = mt * 16 + l15;
      int off = (row * 1024 + (kt * 32 + l4 * 8) * 2) ^ SW(row);
      ah[mt] = *(const bf16x8*)(smem + off);
    }
    {
      int n = w * 16 + l15;
      int boff = n * 64 + l4 * 16;
      bh = *(const bf16x8*)(buf + boff);
      bl = *(const bf16x8*)(buf + 8192 + boff);
    }
#pragma unroll
    for (int mt = 0; mt < 4; mt++) {
      acc2[mt] = __builtin_amdgcn_mfma_f32_16x16x32_bf16(ah[mt], bh, acc2[mt], 0, 0, 0);
      acc2[mt] = __builtin_amdgcn_mfma_f32_16x16x32_bf16(ah[mt], bl, acc2[mt], 0, 0, 0);
    }
    __syncthreads();
  }

  // ---------------- mx2 -> LDS f32 [64][128], row-swizzled ----------------
#pragma unroll
  for (int mt = 0; mt < 4; mt++)
#pragma unroll
    for (int r = 0; r < 4; r++) {
      int row = mt * 16 + l4 * 4 + r;
      int col = w * 16 + l15;
      *(float*)(smem + ((row * 512 + col * 4) ^ SW(row))) = acc2[mt][r];
    }
  __syncthreads();

  // ---------------- layer-2 epilogue (8 threads/row, 16 cols each) ----------------
  {
    const int c0 = cc * 16;
    float4 g[4], bw[4];
#pragma unroll
    for (int ch = 0; ch < 4; ch++)
      g[ch] = *(const float4*)(smem + ((rr * 512 + (c0 + ch * 4) * 4) ^ SW(rr)));
#pragma unroll
    for (int ch = 0; ch < 4; ch++) {
      int c = c0 + ch * 4;
      bw[ch] = *(const float4*)(smem + 131072 + 2048 + ((c * 4) ^ (((c >> 4) & 7) << 4)));
    }
    float ss = 0.f;
#pragma unroll
    for (int ch = 0; ch < 4; ch++) ss += dot4(g[ch], g[ch]);
    ss = red8f(ss);
    float mxn = fmaxf(sqrtf(ss), MINN);
    float tv = tanhf(mxn / xn2 * atanhf(fminf(xn2, ATEPS)));
    float sc = tv / mxn;
    float hn = tv;
    if (hn > MAXN) { sc *= MAXN / hn; hn = MAXN; }
#pragma unroll
    for (int ch = 0; ch < 4; ch++) SCL4(g[ch], sc);

    float xyp = 0.f;
#pragma unroll
    for (int ch = 0; ch < 4; ch++) xyp += dot4(g[ch], bw[ch]);
    float xy = red8f(xyp);
    float y2 = sy[1];
    float x2 = hn * hn;
    float A  = 1.f + 2.f * xy + y2;
    float Bc = 1.f - x2;
    float den = fmaxf(1.f + 2.f * xy + x2 * y2, MINN);
    float Ai = A / den, Bi = Bc / den;
#pragma unroll
    for (int ch = 0; ch < 4; ch++) MADD4(g[ch], Ai, Bi, bw[ch]);
    float g2 = 0.f;
#pragma unroll
    for (int ch = 0; ch < 4; ch++) g2 += dot4(g[ch], g[ch]);
    g2 = red8f(g2);
    float gn = fmaxf(sqrtf(g2), MINN);
    float pf = (gn > MAXN) ? (MAXN / gn) : 1.f;

    float* og = out + (rowBase + rr) * 128 + c0;
#pragma unroll
    for (int ch = 0; ch < 4; ch++) {
      float4 o = g[ch];
      SCL4(o, pf);
      *(float4*)(og + ch * 4) = o;
    }
  }
}

extern "C" void kernel_launch(void* const* d_in, const int* in_sizes, int n_in,
                              void* d_out, int out_size, void* d_ws, size_t ws_size,
                              hipStream_t stream) {
  const float* x  = (const float*)d_in[0];  // [B,256]
  const float* W1 = (const float*)d_in[1];  // [512,256]
  const float* b1 = (const float*)d_in[2];  // [512]
  const float* W2 = (const float*)d_in[3];  // [128,512]
  const float* b2 = (const float*)d_in[4];  // [128]
  float* o = (float*)d_out;

  const int B = in_sizes[0] / 256;

  u16* w1h = (u16*)d_ws;              // [512*256]
  u16* w1l = w1h + 512 * 256;
  u16* w2h = w1l + 512 * 256;         // [128*512]
  u16* w2l = w2h + 128 * 512;         // total 786432 B (same ws footprint as round 1)

  cvtW<<<384, 512, 0, stream>>>(W1, W2, w1h, w1l, w2h, w2l);
  hyper<<<B / 64, 512, 0, stream>>>(x, b1, b2, w1h, w1l, w2h, w2l, o);
}